// Round 3
// baseline (491.342 us; speedup 1.0000x reference)
//
#include <hip/hip_runtime.h>
#include <hip/hip_bf16.h>

typedef unsigned short u16;
typedef unsigned int   u32;
typedef unsigned long long u64;
typedef long long      i64;
typedef __attribute__((ext_vector_type(8))) short short8;  // 8 bf16 raw
typedef __attribute__((ext_vector_type(4))) float f32x4;

#define HD 128   // hidden / input feature dim
#define OUTD 64  // final output dim
#define BSH 8            // bucket shift: 256 nodes per bucket (power of 2, <=8 for u32 pack!)
#define NBKT_MAX 512     // max buckets (N <= 128K; also keeps src in 24 bits)
#define PCHUNK 2048      // edges per block in partition phase 1
#define GCUR_STRIDE 16   // ints; 64 B padding to avoid atomic line contention

__device__ __forceinline__ float bf2f(u16 u){ union{u32 i; float f;} x; x.i=((u32)u)<<16; return x.f; }
__device__ __forceinline__ u16 f2bf(float f){ __hip_bfloat16 h=__float2bfloat16(f); return *reinterpret_cast<u16*>(&h); }

__device__ __forceinline__ short8 load8(const float* p){
  f32x4 lo = *reinterpret_cast<const f32x4*>(p);
  f32x4 hi = *reinterpret_cast<const f32x4*>(p + 4);
  short8 r;
  #pragma unroll
  for (int j=0;j<4;j++){ r[j]=(short)f2bf(lo[j]); r[4+j]=(short)f2bf(hi[j]); }
  return r;
}
__device__ __forceinline__ short8 load8(const u16* p){
  return *reinterpret_cast<const short8*>(p);
}

// index fetch that handles int32-vs-int64 delivery (flag: 1 = int32, 0 = int64)
__device__ __forceinline__ int idx_at(const void* p, int i, int is32){
  return is32 ? ((const int*)p)[i] : (int)((const i64*)p)[i];
}

// ---- zero-fill output (ws-too-small fallback signal) ----------------------
__global__ void k_zero_out(float* __restrict__ out, int n){
  int i = blockIdx.x*256 + threadIdx.x;
  if (i < n) out[i] = 0.f;
}

// ---- init: block 0 = zero+detect dtype flags; blocks >=1 zero cnt & pooled -
// flags[0]=edge int32?, flags[1]=batch int32?, flags[2]=batch unsorted?
__global__ __launch_bounds__(256) void k_init(
    const u32* __restrict__ ei, const u32* __restrict__ bw,
    int* __restrict__ flags, int* __restrict__ cnt, float* __restrict__ pooled,
    int npairs_e, int npairs_b, int N, int npool)
{
  int t = threadIdx.x;
  if (blockIdx.x == 0){
    if (t < 16) flags[t] = 0;
    __syncthreads();
    for (int i=t; i<npairs_e; i+=256) if (ei[2*i+1] != 0) atomicOr(&flags[0], 1);
    for (int i=t; i<npairs_b; i+=256) if (bw[2*i+1] != 0) atomicOr(&flags[1], 1);
  } else {
    int i = (blockIdx.x-1)*256 + t;
    if (i < N)     cnt[i] = 0;
    if (i < npool) pooled[i] = 0.f;
  }
}

// ---- fused: blocks [0,NBc) sortedness check; blocks [NBc,..) degree count --
__global__ __launch_bounds__(256) void k_sorted_count(
    const void* __restrict__ batch, const void* __restrict__ ei,
    int* __restrict__ flags, int* __restrict__ cnt, int n, int E, int NBc)
{
  if (blockIdx.x < NBc){
    int i = blockIdx.x*256 + threadIdx.x;
    if (i < n-1){
      int is32 = flags[1];
      if (idx_at(batch, i, is32) > idx_at(batch, i+1, is32)) atomicOr(&flags[2], 1);
    }
  } else {
    int e = (blockIdx.x - NBc)*256 + threadIdx.x;
    if (e < E){
      int d = idx_at(ei, E + e, flags[0]);   // dst = row 1
      atomicAdd(&cnt[d], 1);
    }
  }
}

__global__ void k_chunk_sums(const int* __restrict__ cnt, int* __restrict__ csum, int n){
  __shared__ int sd[256];
  int c=blockIdx.x, t=threadIdx.x;
  int base=c*1024+t*4, s=0;
  #pragma unroll
  for (int k=0;k<4;k++){ int i=base+k; if(i<n) s+=cnt[i]; }
  sd[t]=s; __syncthreads();
  for (int o=128;o>0;o>>=1){ if(t<o) sd[t]+=sd[t+o]; __syncthreads(); }
  if (t==0) csum[c]=sd[0];
}

// scan chunks -> row_ptr, dinv, padded bucket cursors (gcur). The chunk-total
// scan is done inline per block (csum holds RAW sums; nch <= 1024), removing
// the separate single-block k_scan_totals dispatch.
__global__ void k_scan_chunks(const int* __restrict__ cnt, const int* __restrict__ csum,
                              int* __restrict__ row_ptr, int* __restrict__ gcur,
                              float* __restrict__ dinv, int n, int total, int nch){
  __shared__ int st[256];
  __shared__ int sd[256];
  int c=blockIdx.x, t=threadIdx.x;

  // inline exclusive prefix of csum at chunk c (all threads compute same)
  int s4=0;
  #pragma unroll
  for (int k=0;k<4;k++){ int i=t*4+k; if(i<nch) s4+=csum[i]; }
  st[t]=s4; __syncthreads();
  for (int o=1;o<256;o<<=1){ int x=(t>=o)?st[t-o]:0; __syncthreads(); st[t]+=x; __syncthreads(); }
  int cq=c>>2, cr=c&3;
  int cbase=(cq>0)?st[cq-1]:0;
  for (int k=0;k<cr;k++) cbase += csum[cq*4+k];

  int base=c*1024+t*4;
  int v[4], s=0;
  #pragma unroll
  for (int k=0;k<4;k++){ int i=base+k; v[k]=(i<n)?cnt[i]:0; s+=v[k]; }
  sd[t]=s; __syncthreads();
  for (int o=1;o<256;o<<=1){ int x=(t>=o)?sd[t-o]:0; __syncthreads(); sd[t]+=x; __syncthreads(); }
  int pre = cbase + ((t>0)?sd[t-1]:0);
  #pragma unroll
  for (int k=0;k<4;k++){
    int i=base+k;
    if (i<n){
      row_ptr[i]=pre;
      if ((i & ((1<<BSH)-1)) == 0) gcur[(i>>BSH)*GCUR_STRIDE] = pre;
      dinv[i]=rsqrtf((float)(v[k]+1));   // +1 self-loop; always >0
      pre+=v[k];
    }
  }
  if (c==0 && t==0) row_ptr[n]=total;
}

// ---- MFMA GEMM body (shared by fused and standalone kernels) --------------
// G = dinv ⊙ (X @ W), bf16 out. Grid sized so each wave does exactly 2 tiles.
template <typename TIN>
__device__ __forceinline__ void gemm_body(
    int bid, int nblocks, const TIN* __restrict__ X, const float* __restrict__ W,
    const float* __restrict__ dinv, u16* __restrict__ Gout, int nrows)
{
  int lane = threadIdx.x & 63;
  int wv   = threadIdx.x >> 6;
  int n    = lane & 15, quad = lane >> 4;

  short8 bf[8][4];
  #pragma unroll
  for (int t=0;t<8;t++)
    #pragma unroll
    for (int c=0;c<4;c++)
      #pragma unroll
      for (int j=0;j<8;j++)
        bf[t][c][j] = (short)f2bf(W[(c*32 + quad*8 + j)*HD + t*16 + n]);

  int ntiles = (nrows+15)>>4;
  int stride = nblocks*4;
  for (int tile = bid*4 + wv; tile < ntiles; tile += stride){
    int ra = tile*16 + n;                 // lane's A row (m = lane&15)
    if (ra >= nrows) ra = nrows-1;
    const TIN* xp = X + (size_t)ra*HD + quad*8;
    short8 a[4];
    #pragma unroll
    for (int c=0;c<4;c++) a[c] = load8(xp + c*32);

    f32x4 acc[8];
    #pragma unroll
    for (int t=0;t<8;t++) acc[t] = (f32x4){0.f,0.f,0.f,0.f};
    #pragma unroll
    for (int c=0;c<4;c++)
      #pragma unroll
      for (int t=0;t<8;t++)
        acc[t] = __builtin_amdgcn_mfma_f32_16x16x32_bf16(a[c], bf[t][c], acc[t], 0,0,0);

    float dv[4]; int rw[4];
    #pragma unroll
    for (int r=0;r<4;r++){
      int row = tile*16 + quad*4 + r;
      rw[r]=row; dv[r]=(row<nrows)?dinv[row]:0.f;
    }
    #pragma unroll
    for (int t=0;t<8;t++)
      #pragma unroll
      for (int r=0;r<4;r++){
        int row = rw[r];
        if (row < nrows)
          Gout[(size_t)row*HD + t*16 + n] = f2bf(dv[r]*acc[t][r]);
      }
  }
}

// ---- fused: blocks [0,npart) = edge partition phase 1; rest = layer-1 GEMM.
// The two are data-independent (both need only scan output) -> they execute
// concurrently in one dispatch instead of serially in two.
// pairs entry: src in bits [0,24), dst_local (d & 255) in bits [24,32).
__global__ __launch_bounds__(256) void k_part1_gemm1(
    const void* __restrict__ ei, const int* __restrict__ flags,
    int* __restrict__ gcur, u32* __restrict__ pairs, int E,
    const float* __restrict__ x, const float* __restrict__ W1,
    const float* __restrict__ dinv, u16* __restrict__ gbuf, int N,
    int npart, int ngemm)
{
  if (blockIdx.x >= npart){
    gemm_body<float>(blockIdx.x - npart, ngemm, x, W1, dinv, gbuf, N);
    return;
  }

  __shared__ int hist[NBKT_MAX];
  __shared__ int soff[NBKT_MAX];
  __shared__ int gb[NBKT_MAX];
  __shared__ int scant[256];
  __shared__ u32 stage[PCHUNK];
  __shared__ u16 sbkt[PCHUNK];

  int tid = threadIdx.x;
  hist[tid]=0; hist[tid+256]=0;
  __syncthreads();

  int base = blockIdx.x*PCHUNK;
  int is32 = flags[0];
  int d[PCHUNK/256], s[PCHUNK/256];
  #pragma unroll
  for (int k=0;k<PCHUNK/256;k++){
    int e = base + k*256 + tid;
    if (e < E){
      d[k]=idx_at(ei,E+e,is32); s[k]=idx_at(ei,e,is32);
      atomicAdd(&hist[d[k]>>BSH],1);
    } else d[k]=-1;
  }
  __syncthreads();

  // scan 512 buckets with 256 threads (2 each)
  int a0=hist[2*tid], a1=hist[2*tid+1];
  scant[tid]=a0+a1; __syncthreads();
  for (int o=1;o<256;o<<=1){ int x2=(tid>=o)?scant[tid-o]:0; __syncthreads(); scant[tid]+=x2; __syncthreads(); }
  int pre = (tid>0)?scant[tid-1]:0;
  soff[2*tid]=pre; soff[2*tid+1]=pre+a0;
  if (a0) gb[2*tid]   = atomicAdd(&gcur[(2*tid)*GCUR_STRIDE],   a0); else gb[2*tid]=0;
  if (a1) gb[2*tid+1] = atomicAdd(&gcur[(2*tid+1)*GCUR_STRIDE], a1); else gb[2*tid+1]=0;
  hist[2*tid]=0; hist[2*tid+1]=0;
  __syncthreads();

  // scatter into LDS stage ordered by bucket
  #pragma unroll
  for (int k=0;k<PCHUNK/256;k++){
    if (d[k]>=0){
      int b = d[k]>>BSH;
      int loc = soff[b] + atomicAdd(&hist[b],1);
      stage[loc] = (u32)s[k] | ((u32)(d[k] & ((1<<BSH)-1)) << 24);
      sbkt[loc] = (u16)b;
    }
  }
  __syncthreads();

  // coalesced flush: consecutive slots of a bucket -> consecutive global pairs
  int cnt_edges = E - base; if (cnt_edges > PCHUNK) cnt_edges = PCHUNK;
  for (int i=tid; i<cnt_edges; i+=256){
    int b = sbkt[i];
    pairs[(size_t)gb[b] + (i - soff[b])] = stage[i];
  }
}

// ---- standalone GEMM for layer 2 ------------------------------------------
template <typename TIN>
__global__ __launch_bounds__(256) void k_gemm_scale(
    const TIN* __restrict__ X, const float* __restrict__ W,
    const float* __restrict__ dinv, u16* __restrict__ Gout, int nrows)
{
  gemm_body<TIN>(blockIdx.x, gridDim.x, X, W, dinv, Gout, nrows);
}

// ---- phase 2: per-bucket exact scatter, LDS cursors -----------------------
__global__ __launch_bounds__(256) void k_part2(
    const u32* __restrict__ pairs, const int* __restrict__ row_ptr,
    int* __restrict__ colv, int N)
{
  __shared__ int lcur[1<<BSH];
  int b = blockIdx.x;
  int n0 = b<<BSH;
  int n1 = (b+1)<<BSH; if (n1 > N) n1 = N;
  int nn = n1 - n0;
  for (int i=threadIdx.x; i<nn; i+=256) lcur[i] = row_ptr[n0+i];
  __syncthreads();
  int lo = row_ptr[n0], hi = row_ptr[n1];
  for (int i = lo + threadIdx.x; i < hi; i += 256){
    u32 p = pairs[i];
    int s = (int)(p & 0xFFFFFFu), dl = (int)(p >> 24);
    int pos = atomicAdd(&lcur[dl], 1);
    colv[pos] = s;
  }
}

// ---- aggregation (proven, FROZEN): h[i]=relu(dinv[i]*(g[i]+sum g[src])+b) -
// one wave per node; lane handles 2 features (u32 = full 256 B row per
// instruction); 8-deep unroll; serial tail. At the XCD-compulsory fetch floor
// (FETCH ~190MB ~ 8 x 25.6MB) and random-64B service ceiling (~2.9 TB/s).
// Do NOT add instructions here (r1's padded variant regressed 25%).
__global__ __launch_bounds__(256) void k_aggregate(
    const u16* __restrict__ g, const int* __restrict__ row_ptr,
    const int* __restrict__ colv, const float* __restrict__ dinv,
    const float* __restrict__ bias, u16* __restrict__ h, int n)
{
  int node = blockIdx.x*4 + (threadIdx.x>>6);
  if (node >= n) return;
  int lane = threadIdx.x & 63;
  int off = lane*2;

  u32 u = *reinterpret_cast<const u32*>(g + (size_t)node*HD + off);   // self-loop term
  float ax = bf2f((u16)(u&0xffffu)), ay = bf2f((u16)(u>>16));

  int s = row_ptr[node], e = row_ptr[node+1];
  int i = s;
  for (; i+8<=e; i+=8){
    u32 v[8];
    #pragma unroll
    for (int j=0;j<8;j++){
      int sj = colv[i+j];
      v[j] = *reinterpret_cast<const u32*>(g+(size_t)sj*HD+off);
    }
    #pragma unroll
    for (int j=0;j<8;j++){
      ax += bf2f((u16)(v[j]&0xffffu));
      ay += bf2f((u16)(v[j]>>16));
    }
  }
  for (; i<e; i++){
    u32 v=*reinterpret_cast<const u32*>(g+(size_t)colv[i]*HD+off);
    ax += bf2f((u16)(v&0xffffu)); ay += bf2f((u16)(v>>16));
  }

  float dv = dinv[node];
  float rx = fmaxf(fmaf(dv, ax, bias[off]),   0.f);
  float ry = fmaxf(fmaf(dv, ay, bias[off+1]), 0.f);
  *reinterpret_cast<u32*>(h + (size_t)node*HD + off) = (u32)f2bf(rx) | ((u32)f2bf(ry)<<16);
}

// ---- global_add_pool + final linear, sorted path (fused) ------------------
__device__ __forceinline__ int lowerb(const void* a, int is32, int n, int key){
  int lo=0, hi=n;
  while (lo<hi){
    int mid=(lo+hi)>>1;
    if (idx_at(a, mid, is32) < key) lo=mid+1; else hi=mid;
  }
  return lo;
}

__global__ __launch_bounds__(256) void k_pool_final_sorted(
    const u16* __restrict__ h, const void* __restrict__ batch,
    const int* __restrict__ flags, const float* __restrict__ Wl,
    const float* __restrict__ bl, float* __restrict__ out, int n)
{
  if (flags[2]) return;                     // unsorted -> atomic path handles it
  __shared__ float sd[4][128];
  __shared__ float ps[128];
  __shared__ float racc[4][64];
  int gid = blockIdx.x, t = threadIdx.x;
  int w = t >> 6, lane = t & 63;
  int off = lane*2;
  int is32 = flags[1];
  int lo = lowerb(batch, is32, n, gid), hi = lowerb(batch, is32, n, gid+1);

  float ax = 0.f, ay = 0.f;
  int i = lo + w;                           // waves stride rows by 4
  for (; i + 12 < hi; i += 16){
    u32 v0 = *reinterpret_cast<const u32*>(h + (size_t)(i   )*HD + off);
    u32 v1 = *reinterpret_cast<const u32*>(h + (size_t)(i+ 4)*HD + off);
    u32 v2 = *reinterpret_cast<const u32*>(h + (size_t)(i+ 8)*HD + off);
    u32 v3 = *reinterpret_cast<const u32*>(h + (size_t)(i+12)*HD + off);
    ax += bf2f((u16)(v0&0xffffu)) + bf2f((u16)(v1&0xffffu))
        + bf2f((u16)(v2&0xffffu)) + bf2f((u16)(v3&0xffffu));
    ay += bf2f((u16)(v0>>16)) + bf2f((u16)(v1>>16))
        + bf2f((u16)(v2>>16)) + bf2f((u16)(v3>>16));
  }
  for (; i < hi; i += 4){
    u32 v = *reinterpret_cast<const u32*>(h + (size_t)i*HD + off);
    ax += bf2f((u16)(v&0xffffu)); ay += bf2f((u16)(v>>16));
  }
  sd[w][off] = ax; sd[w][off+1] = ay;
  __syncthreads();
  if (t < 128) ps[t] = sd[0][t] + sd[1][t] + sd[2][t] + sd[3][t];
  __syncthreads();

  // out[gid] = ps @ Wl + bl : 4 k-segments of 32, 64 outputs each
  int o = t & 63, seg = t >> 6;
  float acc = 0.f;
  #pragma unroll
  for (int kk=0; kk<32; kk++){
    int k = seg*32 + kk;
    acc = fmaf(ps[k], Wl[k*OUTD + o], acc);
  }
  racc[seg][o] = acc;
  __syncthreads();
  if (t < 64)
    out[(size_t)gid*OUTD + t] = bl[t] + racc[0][t] + racc[1][t] + racc[2][t] + racc[3][t];
}

// ---- global_add_pool, fallback: atomicAdd per node (any ordering) ---------
__global__ __launch_bounds__(256) void k_pool_atomic(
    const u16* __restrict__ h, const void* __restrict__ batch,
    const int* __restrict__ flags, float* __restrict__ pooled, int n)
{
  if (!flags[2]) return;                    // sorted path already did it
  int node = blockIdx.x*4 + (threadIdx.x>>6);
  if (node >= n) return;
  int lane = threadIdx.x & 63;
  int off = lane*2;
  int g = idx_at(batch, node, flags[1]);
  u32 v = *reinterpret_cast<const u32*>(h + (size_t)node*HD + off);
  atomicAdd(&pooled[(size_t)g*HD + off],     bf2f((u16)(v&0xffffu)));
  atomicAdd(&pooled[(size_t)g*HD + off + 1], bf2f((u16)(v>>16)));
}

// ---- final linear, unsorted path only: out = pooled @ Wl + bl -------------
__global__ void k_final(const float* __restrict__ pooled, const float* __restrict__ Wl,
                        const float* __restrict__ bl, const int* __restrict__ flags,
                        float* __restrict__ out){
  if (!flags[2]) return;                    // sorted path wrote out already
  int gid = blockIdx.x, t = threadIdx.x;   // 64 threads
  float acc = bl[t];
  const float* p = pooled + gid*HD;
  #pragma unroll 8
  for (int k=0;k<HD;k++) acc = fmaf(p[k], Wl[k*OUTD + t], acc);
  out[gid*OUTD + t] = acc;
}

extern "C" void kernel_launch(void* const* d_in, const int* in_sizes, int n_in,
                              void* d_out, int out_size, void* d_ws, size_t ws_size,
                              hipStream_t stream)
{
  const float* x   = (const float*)d_in[0];
  const void*  ei  = d_in[1];
  const void*  bat = d_in[2];
  const float* W1  = (const float*)d_in[3];
  const float* b1  = (const float*)d_in[4];
  const float* W2  = (const float*)d_in[5];
  const float* b2  = (const float*)d_in[6];
  const float* Wl  = (const float*)d_in[7];
  const float* bl  = (const float*)d_in[8];
  float* out = (float*)d_out;

  int N = in_sizes[0] / HD;
  int E = in_sizes[1] / 2;
  int G = out_size / OUTD;
  int NCH = (N + 1023) / 1024;
  int nbins = (N + (1<<BSH) - 1) >> BSH;   // 256 nodes per bin

  char* w = (char*)d_ws;
  size_t o = 0;
  auto alloc = [&](size_t b){ void* p = w + o; o += (b + 255) & ~(size_t)255; return p; };
  int*   cnt     = (int*)  alloc((size_t)N*4);
  int*   row_ptr = (int*)  alloc((size_t)(N+1)*4);
  int*   csum    = (int*)  alloc((size_t)NCH*4);
  int*   colv    = (int*)  alloc((size_t)E*4);
  u32*   pairs   = (u32*)  alloc((size_t)E*4);
  int*   gcur    = (int*)  alloc((size_t)NBKT_MAX*GCUR_STRIDE*4);
  float* dinv    = (float*)alloc((size_t)N*4);
  u16*   gbuf    = (u16*)  alloc((size_t)N*HD*2);
  u16*   hbuf    = (u16*)  alloc((size_t)N*HD*2);
  float* pooled  = (float*)alloc((size_t)G*HD*4);
  int*   flags   = (int*)  alloc(256);
  (void)n_in;

  if (o > ws_size || nbins > NBKT_MAX){
    k_zero_out<<<(out_size+255)/256, 256, 0, stream>>>(out, out_size);
    return;
  }

  int npairs_e = 4096; if (npairs_e > E) npairs_e = E;
  int npairs_b = 4096; if (npairs_b > N/2) npairs_b = N/2;
  int npool = G*HD;
  int nzb = (N+255)/256; { int pz = (npool+255)/256; if (pz > nzb) nzb = pz; }

  // 1: zero flags/cnt/pooled + dtype detection (replaces 3 memsets + k_flags)
  k_init<<<1+nzb, 256, 0, stream>>>((const u32*)ei, (const u32*)bat, flags, cnt, pooled,
                                    npairs_e, npairs_b, N, npool);
  // 2: sortedness check (blocks [0,NBc)) + degree count (rest)
  int NBc = (N+255)/256, NBe = (E+255)/256;
  k_sorted_count<<<NBc+NBe, 256, 0, stream>>>(bat, ei, flags, cnt, N, E, NBc);
  // 3-4: scan (chunk-total scan folded into k_scan_chunks)
  k_chunk_sums <<<NCH, 256, 0, stream>>>(cnt, csum, N);
  k_scan_chunks<<<NCH, 256, 0, stream>>>(cnt, csum, row_ptr, gcur, dinv, N, E, NCH);
  // 5: partition phase 1 || layer-1 GEMM (independent -> one fat dispatch)
  int npart = (E + PCHUNK - 1) / PCHUNK;
  int ntiles = (N+15)/16, ngemm = (ntiles+7)/8;   // each wave: exactly 2 tiles
  k_part1_gemm1<<<npart+ngemm, 256, 0, stream>>>(ei, flags, gcur, pairs, E,
                                                 x, W1, dinv, gbuf, N, npart, ngemm);
  // 6: partition phase 2 (exact CSR placement)
  k_part2<<<nbins, 256, 0, stream>>>(pairs, row_ptr, colv, N);
  // 7-9: aggregate L1, GEMM L2, aggregate L2
  k_aggregate <<<(N+3)/4, 256, 0, stream>>>(gbuf, row_ptr, colv, dinv, b1, hbuf, N);
  k_gemm_scale<u16><<<ngemm, 256, 0, stream>>>(hbuf, W2, dinv, gbuf, N);
  k_aggregate <<<(N+3)/4, 256, 0, stream>>>(gbuf, row_ptr, colv, dinv, b2, hbuf, N);
  // 10-12: pool+final (sorted fused path; atomic fallback early-returns)
  k_pool_final_sorted<<<G, 256, 0, stream>>>(hbuf, bat, flags, Wl, bl, out, N);
  k_pool_atomic<<<(N+3)/4, 256, 0, stream>>>(hbuf, bat, flags, pooled, N);
  k_final      <<<G, OUTD, 0, stream>>>(pooled, Wl, bl, flags, out);
}

// Round 4
// 473.738 us; speedup vs baseline: 1.0372x; 1.0372x over previous
//
#include <hip/hip_runtime.h>
#include <hip/hip_bf16.h>

typedef unsigned short u16;
typedef unsigned int   u32;
typedef unsigned long long u64;
typedef long long      i64;
typedef __attribute__((ext_vector_type(8))) short short8;  // 8 bf16 raw
typedef __attribute__((ext_vector_type(4))) float f32x4;

#define HD 128   // hidden / input feature dim
#define OUTD 64  // final output dim
#define BSH 8            // bucket shift: 256 nodes per bucket (power of 2, <=8 for u32 pack!)
#define NBKT_MAX 512     // max buckets (N <= 128K; also keeps src in 24 bits)
#define PCHUNK 2048      // edges per block in partition phase 1
#define GCUR_STRIDE 16   // ints; 64 B padding to avoid atomic line contention

__device__ __forceinline__ float bf2f(u16 u){ union{u32 i; float f;} x; x.i=((u32)u)<<16; return x.f; }
__device__ __forceinline__ u16 f2bf(float f){ __hip_bfloat16 h=__float2bfloat16(f); return *reinterpret_cast<u16*>(&h); }

__device__ __forceinline__ short8 load8(const float* p){
  f32x4 lo = *reinterpret_cast<const f32x4*>(p);
  f32x4 hi = *reinterpret_cast<const f32x4*>(p + 4);
  short8 r;
  #pragma unroll
  for (int j=0;j<4;j++){ r[j]=(short)f2bf(lo[j]); r[4+j]=(short)f2bf(hi[j]); }
  return r;
}
__device__ __forceinline__ short8 load8(const u16* p){
  return *reinterpret_cast<const short8*>(p);
}

// index fetch that handles int32-vs-int64 delivery (flag: 1 = int32, 0 = int64)
__device__ __forceinline__ int idx_at(const void* p, int i, int is32){
  return is32 ? ((const int*)p)[i] : (int)((const i64*)p)[i];
}

// ---- zero-fill output (ws-too-small fallback signal) ----------------------
__global__ void k_zero_out(float* __restrict__ out, int n){
  int i = blockIdx.x*256 + threadIdx.x;
  if (i < n) out[i] = 0.f;
}

// ---- init: block 0 = zero+detect dtype flags; blocks >=1 zero cnt & pooled -
// flags[0]=edge int32?, flags[1]=batch int32?, flags[2]=batch unsorted?
__global__ __launch_bounds__(256) void k_init(
    const u32* __restrict__ ei, const u32* __restrict__ bw,
    int* __restrict__ flags, int* __restrict__ cnt, float* __restrict__ pooled,
    int npairs_e, int npairs_b, int N, int npool)
{
  int t = threadIdx.x;
  if (blockIdx.x == 0){
    if (t < 16) flags[t] = 0;
    __syncthreads();
    for (int i=t; i<npairs_e; i+=256) if (ei[2*i+1] != 0) atomicOr(&flags[0], 1);
    for (int i=t; i<npairs_b; i+=256) if (bw[2*i+1] != 0) atomicOr(&flags[1], 1);
  } else {
    int i = (blockIdx.x-1)*256 + t;
    if (i < N)     cnt[i] = 0;
    if (i < npool) pooled[i] = 0.f;
  }
}

// ---- fused: blocks [0,NBc) sortedness check; blocks [NBc,..) degree count --
__global__ __launch_bounds__(256) void k_sorted_count(
    const void* __restrict__ batch, const void* __restrict__ ei,
    int* __restrict__ flags, int* __restrict__ cnt, int n, int E, int NBc)
{
  if (blockIdx.x < NBc){
    int i = blockIdx.x*256 + threadIdx.x;
    if (i < n-1){
      int is32 = flags[1];
      if (idx_at(batch, i, is32) > idx_at(batch, i+1, is32)) atomicOr(&flags[2], 1);
    }
  } else {
    int e = (blockIdx.x - NBc)*256 + threadIdx.x;
    if (e < E){
      int d = idx_at(ei, E + e, flags[0]);   // dst = row 1
      atomicAdd(&cnt[d], 1);
    }
  }
}

__global__ void k_chunk_sums(const int* __restrict__ cnt, int* __restrict__ csum, int n){
  __shared__ int sd[256];
  int c=blockIdx.x, t=threadIdx.x;
  int base=c*1024+t*4, s=0;
  #pragma unroll
  for (int k=0;k<4;k++){ int i=base+k; if(i<n) s+=cnt[i]; }
  sd[t]=s; __syncthreads();
  for (int o=128;o>0;o>>=1){ if(t<o) sd[t]+=sd[t+o]; __syncthreads(); }
  if (t==0) csum[c]=sd[0];
}

// scan chunks -> row_ptr, dinv, padded bucket cursors (gcur). The chunk-total
// scan is done inline per block (csum holds RAW sums; nch <= 1024), removing
// the separate single-block k_scan_totals dispatch.
__global__ void k_scan_chunks(const int* __restrict__ cnt, const int* __restrict__ csum,
                              int* __restrict__ row_ptr, int* __restrict__ gcur,
                              float* __restrict__ dinv, int n, int total, int nch){
  __shared__ int st[256];
  __shared__ int sd[256];
  int c=blockIdx.x, t=threadIdx.x;

  // inline exclusive prefix of csum at chunk c (all threads compute same)
  int s4=0;
  #pragma unroll
  for (int k=0;k<4;k++){ int i=t*4+k; if(i<nch) s4+=csum[i]; }
  st[t]=s4; __syncthreads();
  for (int o=1;o<256;o<<=1){ int x=(t>=o)?st[t-o]:0; __syncthreads(); st[t]+=x; __syncthreads(); }
  int cq=c>>2, cr=c&3;
  int cbase=(cq>0)?st[cq-1]:0;
  for (int k=0;k<cr;k++) cbase += csum[cq*4+k];

  int base=c*1024+t*4;
  int v[4], s=0;
  #pragma unroll
  for (int k=0;k<4;k++){ int i=base+k; v[k]=(i<n)?cnt[i]:0; s+=v[k]; }
  sd[t]=s; __syncthreads();
  for (int o=1;o<256;o<<=1){ int x=(t>=o)?sd[t-o]:0; __syncthreads(); sd[t]+=x; __syncthreads(); }
  int pre = cbase + ((t>0)?sd[t-1]:0);
  #pragma unroll
  for (int k=0;k<4;k++){
    int i=base+k;
    if (i<n){
      row_ptr[i]=pre;
      if ((i & ((1<<BSH)-1)) == 0) gcur[(i>>BSH)*GCUR_STRIDE] = pre;
      dinv[i]=rsqrtf((float)(v[k]+1));   // +1 self-loop; always >0
      pre+=v[k];
    }
  }
  if (c==0 && t==0) row_ptr[n]=total;
}

// ---- phase 1: LDS-staged partition of edges into dst-buckets --------------
// STANDALONE kernel (low VGPR): r3's fat-fuse with the GEMM forced 144 VGPRs
// on these blocks and cut occupancy 8->3 blocks/CU (91 us, all pipes idle).
// pairs entry: src in bits [0,24), dst_local (d & 255) in bits [24,32).
__global__ __launch_bounds__(256) void k_part1(
    const void* __restrict__ ei, const int* __restrict__ flags,
    int* __restrict__ gcur, u32* __restrict__ pairs, int E)
{
  __shared__ int hist[NBKT_MAX];
  __shared__ int soff[NBKT_MAX];
  __shared__ int gb[NBKT_MAX];
  __shared__ int scant[256];
  __shared__ u32 stage[PCHUNK];
  __shared__ u16 sbkt[PCHUNK];

  int tid = threadIdx.x;
  hist[tid]=0; hist[tid+256]=0;
  __syncthreads();

  int base = blockIdx.x*PCHUNK;
  int is32 = flags[0];
  int d[PCHUNK/256], s[PCHUNK/256];
  #pragma unroll
  for (int k=0;k<PCHUNK/256;k++){
    int e = base + k*256 + tid;
    if (e < E){
      d[k]=idx_at(ei,E+e,is32); s[k]=idx_at(ei,e,is32);
      atomicAdd(&hist[d[k]>>BSH],1);
    } else d[k]=-1;
  }
  __syncthreads();

  // scan 512 buckets with 256 threads (2 each)
  int a0=hist[2*tid], a1=hist[2*tid+1];
  scant[tid]=a0+a1; __syncthreads();
  for (int o=1;o<256;o<<=1){ int x2=(tid>=o)?scant[tid-o]:0; __syncthreads(); scant[tid]+=x2; __syncthreads(); }
  int pre = (tid>0)?scant[tid-1]:0;
  soff[2*tid]=pre; soff[2*tid+1]=pre+a0;
  if (a0) gb[2*tid]   = atomicAdd(&gcur[(2*tid)*GCUR_STRIDE],   a0); else gb[2*tid]=0;
  if (a1) gb[2*tid+1] = atomicAdd(&gcur[(2*tid+1)*GCUR_STRIDE], a1); else gb[2*tid+1]=0;
  hist[2*tid]=0; hist[2*tid+1]=0;
  __syncthreads();

  // scatter into LDS stage ordered by bucket
  #pragma unroll
  for (int k=0;k<PCHUNK/256;k++){
    if (d[k]>=0){
      int b = d[k]>>BSH;
      int loc = soff[b] + atomicAdd(&hist[b],1);
      stage[loc] = (u32)s[k] | ((u32)(d[k] & ((1<<BSH)-1)) << 24);
      sbkt[loc] = (u16)b;
    }
  }
  __syncthreads();

  // coalesced flush: consecutive slots of a bucket -> consecutive global pairs
  int cnt_edges = E - base; if (cnt_edges > PCHUNK) cnt_edges = PCHUNK;
  for (int i=tid; i<cnt_edges; i+=256){
    int b = sbkt[i];
    pairs[(size_t)gb[b] + (i - soff[b])] = stage[i];
  }
}

// ---- MFMA GEMM: G = dinv ⊙ (X @ W), bf16 out. 512-block grid (proven r2) --
template <typename TIN>
__global__ __launch_bounds__(256) void k_gemm_scale(
    const TIN* __restrict__ X, const float* __restrict__ W,
    const float* __restrict__ dinv, u16* __restrict__ Gout, int nrows)
{
  int lane = threadIdx.x & 63;
  int wv   = threadIdx.x >> 6;
  int n    = lane & 15, quad = lane >> 4;

  short8 bf[8][4];
  #pragma unroll
  for (int t=0;t<8;t++)
    #pragma unroll
    for (int c=0;c<4;c++)
      #pragma unroll
      for (int j=0;j<8;j++)
        bf[t][c][j] = (short)f2bf(W[(c*32 + quad*8 + j)*HD + t*16 + n]);

  int ntiles = (nrows+15)>>4;
  int stride = gridDim.x*4;
  for (int tile = blockIdx.x*4 + wv; tile < ntiles; tile += stride){
    int ra = tile*16 + n;                 // lane's A row (m = lane&15)
    if (ra >= nrows) ra = nrows-1;
    const TIN* xp = X + (size_t)ra*HD + quad*8;
    short8 a[4];
    #pragma unroll
    for (int c=0;c<4;c++) a[c] = load8(xp + c*32);

    f32x4 acc[8];
    #pragma unroll
    for (int t=0;t<8;t++) acc[t] = (f32x4){0.f,0.f,0.f,0.f};
    #pragma unroll
    for (int c=0;c<4;c++)
      #pragma unroll
      for (int t=0;t<8;t++)
        acc[t] = __builtin_amdgcn_mfma_f32_16x16x32_bf16(a[c], bf[t][c], acc[t], 0,0,0);

    float dv[4]; int rw[4];
    #pragma unroll
    for (int r=0;r<4;r++){
      int row = tile*16 + quad*4 + r;
      rw[r]=row; dv[r]=(row<nrows)?dinv[row]:0.f;
    }
    #pragma unroll
    for (int t=0;t<8;t++)
      #pragma unroll
      for (int r=0;r<4;r++){
        int row = rw[r];
        if (row < nrows)
          Gout[(size_t)row*HD + t*16 + n] = f2bf(dv[r]*acc[t][r]);
      }
  }
}

// ---- phase 2: per-bucket exact scatter, LDS cursors -----------------------
__global__ __launch_bounds__(256) void k_part2(
    const u32* __restrict__ pairs, const int* __restrict__ row_ptr,
    int* __restrict__ colv, int N)
{
  __shared__ int lcur[1<<BSH];
  int b = blockIdx.x;
  int n0 = b<<BSH;
  int n1 = (b+1)<<BSH; if (n1 > N) n1 = N;
  int nn = n1 - n0;
  for (int i=threadIdx.x; i<nn; i+=256) lcur[i] = row_ptr[n0+i];
  __syncthreads();
  int lo = row_ptr[n0], hi = row_ptr[n1];
  for (int i = lo + threadIdx.x; i < hi; i += 256){
    u32 p = pairs[i];
    int s = (int)(p & 0xFFFFFFu), dl = (int)(p >> 24);
    int pos = atomicAdd(&lcur[dl], 1);
    colv[pos] = s;
  }
}

// ---- aggregation (proven, FROZEN): h[i]=relu(dinv[i]*(g[i]+sum g[src])+b) -
// one wave per node; lane handles 2 features (u32 = full 256 B row per
// instruction); 8-deep unroll; serial tail. At the XCD-compulsory fetch floor
// (FETCH ~190MB ~ 8 x 25.6MB) and random-64B service ceiling (~2.9 TB/s).
// Do NOT add instructions here (r1's padded variant regressed 25%).
__global__ __launch_bounds__(256) void k_aggregate(
    const u16* __restrict__ g, const int* __restrict__ row_ptr,
    const int* __restrict__ colv, const float* __restrict__ dinv,
    const float* __restrict__ bias, u16* __restrict__ h, int n)
{
  int node = blockIdx.x*4 + (threadIdx.x>>6);
  if (node >= n) return;
  int lane = threadIdx.x & 63;
  int off = lane*2;

  u32 u = *reinterpret_cast<const u32*>(g + (size_t)node*HD + off);   // self-loop term
  float ax = bf2f((u16)(u&0xffffu)), ay = bf2f((u16)(u>>16));

  int s = row_ptr[node], e = row_ptr[node+1];
  int i = s;
  for (; i+8<=e; i+=8){
    u32 v[8];
    #pragma unroll
    for (int j=0;j<8;j++){
      int sj = colv[i+j];
      v[j] = *reinterpret_cast<const u32*>(g+(size_t)sj*HD+off);
    }
    #pragma unroll
    for (int j=0;j<8;j++){
      ax += bf2f((u16)(v[j]&0xffffu));
      ay += bf2f((u16)(v[j]>>16));
    }
  }
  for (; i<e; i++){
    u32 v=*reinterpret_cast<const u32*>(g+(size_t)colv[i]*HD+off);
    ax += bf2f((u16)(v&0xffffu)); ay += bf2f((u16)(v>>16));
  }

  float dv = dinv[node];
  float rx = fmaxf(fmaf(dv, ax, bias[off]),   0.f);
  float ry = fmaxf(fmaf(dv, ay, bias[off+1]), 0.f);
  *reinterpret_cast<u32*>(h + (size_t)node*HD + off) = (u32)f2bf(rx) | ((u32)f2bf(ry)<<16);
}

// ---- global_add_pool + final linear, sorted path (fused) ------------------
__device__ __forceinline__ int lowerb(const void* a, int is32, int n, int key){
  int lo=0, hi=n;
  while (lo<hi){
    int mid=(lo+hi)>>1;
    if (idx_at(a, mid, is32) < key) lo=mid+1; else hi=mid;
  }
  return lo;
}

__global__ __launch_bounds__(256) void k_pool_final_sorted(
    const u16* __restrict__ h, const void* __restrict__ batch,
    const int* __restrict__ flags, const float* __restrict__ Wl,
    const float* __restrict__ bl, float* __restrict__ out, int n)
{
  if (flags[2]) return;                     // unsorted -> atomic path handles it
  __shared__ float sd[4][128];
  __shared__ float ps[128];
  __shared__ float racc[4][64];
  int gid = blockIdx.x, t = threadIdx.x;
  int w = t >> 6, lane = t & 63;
  int off = lane*2;
  int is32 = flags[1];
  int lo = lowerb(batch, is32, n, gid), hi = lowerb(batch, is32, n, gid+1);

  float ax = 0.f, ay = 0.f;
  int i = lo + w;                           // waves stride rows by 4
  for (; i + 12 < hi; i += 16){
    u32 v0 = *reinterpret_cast<const u32*>(h + (size_t)(i   )*HD + off);
    u32 v1 = *reinterpret_cast<const u32*>(h + (size_t)(i+ 4)*HD + off);
    u32 v2 = *reinterpret_cast<const u32*>(h + (size_t)(i+ 8)*HD + off);
    u32 v3 = *reinterpret_cast<const u32*>(h + (size_t)(i+12)*HD + off);
    ax += bf2f((u16)(v0&0xffffu)) + bf2f((u16)(v1&0xffffu))
        + bf2f((u16)(v2&0xffffu)) + bf2f((u16)(v3&0xffffu));
    ay += bf2f((u16)(v0>>16)) + bf2f((u16)(v1>>16))
        + bf2f((u16)(v2>>16)) + bf2f((u16)(v3>>16));
  }
  for (; i < hi; i += 4){
    u32 v = *reinterpret_cast<const u32*>(h + (size_t)i*HD + off);
    ax += bf2f((u16)(v&0xffffu)); ay += bf2f((u16)(v>>16));
  }
  sd[w][off] = ax; sd[w][off+1] = ay;
  __syncthreads();
  if (t < 128) ps[t] = sd[0][t] + sd[1][t] + sd[2][t] + sd[3][t];
  __syncthreads();

  // out[gid] = ps @ Wl + bl : 4 k-segments of 32, 64 outputs each
  int o = t & 63, seg = t >> 6;
  float acc = 0.f;
  #pragma unroll
  for (int kk=0; kk<32; kk++){
    int k = seg*32 + kk;
    acc = fmaf(ps[k], Wl[k*OUTD + o], acc);
  }
  racc[seg][o] = acc;
  __syncthreads();
  if (t < 64)
    out[(size_t)gid*OUTD + t] = bl[t] + racc[0][t] + racc[1][t] + racc[2][t] + racc[3][t];
}

// ---- global_add_pool, fallback: atomicAdd per node (any ordering) ---------
__global__ __launch_bounds__(256) void k_pool_atomic(
    const u16* __restrict__ h, const void* __restrict__ batch,
    const int* __restrict__ flags, float* __restrict__ pooled, int n)
{
  if (!flags[2]) return;                    // sorted path already did it
  int node = blockIdx.x*4 + (threadIdx.x>>6);
  if (node >= n) return;
  int lane = threadIdx.x & 63;
  int off = lane*2;
  int g = idx_at(batch, node, flags[1]);
  u32 v = *reinterpret_cast<const u32*>(h + (size_t)node*HD + off);
  atomicAdd(&pooled[(size_t)g*HD + off],     bf2f((u16)(v&0xffffu)));
  atomicAdd(&pooled[(size_t)g*HD + off + 1], bf2f((u16)(v>>16)));
}

// ---- final linear, unsorted path only: out = pooled @ Wl + bl -------------
__global__ void k_final(const float* __restrict__ pooled, const float* __restrict__ Wl,
                        const float* __restrict__ bl, const int* __restrict__ flags,
                        float* __restrict__ out){
  if (!flags[2]) return;                    // sorted path wrote out already
  int gid = blockIdx.x, t = threadIdx.x;   // 64 threads
  float acc = bl[t];
  const float* p = pooled + gid*HD;
  #pragma unroll 8
  for (int k=0;k<HD;k++) acc = fmaf(p[k], Wl[k*OUTD + t], acc);
  out[gid*OUTD + t] = acc;
}

extern "C" void kernel_launch(void* const* d_in, const int* in_sizes, int n_in,
                              void* d_out, int out_size, void* d_ws, size_t ws_size,
                              hipStream_t stream)
{
  const float* x   = (const float*)d_in[0];
  const void*  ei  = d_in[1];
  const void*  bat = d_in[2];
  const float* W1  = (const float*)d_in[3];
  const float* b1  = (const float*)d_in[4];
  const float* W2  = (const float*)d_in[5];
  const float* b2  = (const float*)d_in[6];
  const float* Wl  = (const float*)d_in[7];
  const float* bl  = (const float*)d_in[8];
  float* out = (float*)d_out;

  int N = in_sizes[0] / HD;
  int E = in_sizes[1] / 2;
  int G = out_size / OUTD;
  int NCH = (N + 1023) / 1024;
  int nbins = (N + (1<<BSH) - 1) >> BSH;   // 256 nodes per bin

  char* w = (char*)d_ws;
  size_t o = 0;
  auto alloc = [&](size_t b){ void* p = w + o; o += (b + 255) & ~(size_t)255; return p; };
  int*   cnt     = (int*)  alloc((size_t)N*4);
  int*   row_ptr = (int*)  alloc((size_t)(N+1)*4);
  int*   csum    = (int*)  alloc((size_t)NCH*4);
  int*   colv    = (int*)  alloc((size_t)E*4);
  u32*   pairs   = (u32*)  alloc((size_t)E*4);
  int*   gcur    = (int*)  alloc((size_t)NBKT_MAX*GCUR_STRIDE*4);
  float* dinv    = (float*)alloc((size_t)N*4);
  u16*   gbuf    = (u16*)  alloc((size_t)N*HD*2);
  u16*   hbuf    = (u16*)  alloc((size_t)N*HD*2);
  float* pooled  = (float*)alloc((size_t)G*HD*4);
  int*   flags   = (int*)  alloc(256);
  (void)n_in;

  if (o > ws_size || nbins > NBKT_MAX){
    k_zero_out<<<(out_size+255)/256, 256, 0, stream>>>(out, out_size);
    return;
  }

  int npairs_e = 4096; if (npairs_e > E) npairs_e = E;
  int npairs_b = 4096; if (npairs_b > N/2) npairs_b = N/2;
  int npool = G*HD;
  int nzb = (N+255)/256; { int pz = (npool+255)/256; if (pz > nzb) nzb = pz; }

  // 1: zero flags/cnt/pooled + dtype detection (replaces 3 memsets + k_flags)
  k_init<<<1+nzb, 256, 0, stream>>>((const u32*)ei, (const u32*)bat, flags, cnt, pooled,
                                    npairs_e, npairs_b, N, npool);
  // 2: sortedness check (blocks [0,NBc)) + degree count (rest)
  int NBc = (N+255)/256, NBe = (E+255)/256;
  k_sorted_count<<<NBc+NBe, 256, 0, stream>>>(bat, ei, flags, cnt, N, E, NBc);
  // 3-4: scan (chunk-total scan folded into k_scan_chunks)
  k_chunk_sums <<<NCH, 256, 0, stream>>>(cnt, csum, N);
  k_scan_chunks<<<NCH, 256, 0, stream>>>(cnt, csum, row_ptr, gcur, dinv, N, E, NCH);
  // 5-6: partition (separate dispatches; see k_part1 comment re r3 fusion)
  int npart = (E + PCHUNK - 1) / PCHUNK;
  k_part1<<<npart, 256, 0, stream>>>(ei, flags, gcur, pairs, E);
  k_gemm_scale<float><<<512, 256, 0, stream>>>(x, W1, dinv, gbuf, N);
  k_part2<<<nbins, 256, 0, stream>>>(pairs, row_ptr, colv, N);
  // 7-9: aggregate L1, GEMM L2, aggregate L2
  k_aggregate <<<(N+3)/4, 256, 0, stream>>>(gbuf, row_ptr, colv, dinv, b1, hbuf, N);
  k_gemm_scale<u16><<<512, 256, 0, stream>>>(hbuf, W2, dinv, gbuf, N);
  k_aggregate <<<(N+3)/4, 256, 0, stream>>>(gbuf, row_ptr, colv, dinv, b2, hbuf, N);
  // 10-12: pool+final (sorted fused path; atomic fallback early-returns)
  k_pool_final_sorted<<<G, 256, 0, stream>>>(hbuf, bat, flags, Wl, bl, out, N);
  k_pool_atomic<<<(N+3)/4, 256, 0, stream>>>(hbuf, bat, flags, pooled, N);
  k_final      <<<G, OUTD, 0, stream>>>(pooled, Wl, bl, flags, out);
}

// Round 5
// 422.833 us; speedup vs baseline: 1.1620x; 1.1204x over previous
//
#include <hip/hip_runtime.h>
#include <hip/hip_bf16.h>

typedef unsigned short u16;
typedef unsigned int   u32;
typedef unsigned long long u64;
typedef long long      i64;
typedef __attribute__((ext_vector_type(8))) short short8;  // 8 bf16 raw
typedef __attribute__((ext_vector_type(4))) float f32x4;

#define HD 128   // hidden / input feature dim
#define OUTD 64  // final output dim
#define BSH 8            // bucket shift: 256 nodes per bucket (power of 2, <=8 for u32 pack!)
#define NBKT_MAX 512     // max buckets (N <= 128K; also keeps src in 24 bits)
#define PCHUNK 2048      // edges per block in partition phase 1
#define GCUR_STRIDE 16   // ints; 64 B padding to avoid atomic line contention

__device__ __forceinline__ float bf2f(u16 u){ union{u32 i; float f;} x; x.i=((u32)u)<<16; return x.f; }
__device__ __forceinline__ u16 f2bf(float f){ __hip_bfloat16 h=__float2bfloat16(f); return *reinterpret_cast<u16*>(&h); }
__device__ __forceinline__ float blo(u32 v){ union{u32 i; float f;} x; x.i=v<<16; return x.f; }
__device__ __forceinline__ float bhi(u32 v){ union{u32 i; float f;} x; x.i=v&0xffff0000u; return x.f; }

__device__ __forceinline__ short8 load8(const float* p){
  f32x4 lo = *reinterpret_cast<const f32x4*>(p);
  f32x4 hi = *reinterpret_cast<const f32x4*>(p + 4);
  short8 r;
  #pragma unroll
  for (int j=0;j<4;j++){ r[j]=(short)f2bf(lo[j]); r[4+j]=(short)f2bf(hi[j]); }
  return r;
}
__device__ __forceinline__ short8 load8(const u16* p){
  return *reinterpret_cast<const short8*>(p);
}

// index fetch that handles int32-vs-int64 delivery (flag: 1 = int32, 0 = int64)
__device__ __forceinline__ int idx_at(const void* p, int i, int is32){
  return is32 ? ((const int*)p)[i] : (int)((const i64*)p)[i];
}

// ---- zero-fill output (ws-too-small fallback signal) ----------------------
__global__ void k_zero_out(float* __restrict__ out, int n){
  int i = blockIdx.x*256 + threadIdx.x;
  if (i < n) out[i] = 0.f;
}

// ---- weight pre-pack: W (f32 row-major) -> bf16 fragment-major ------------
// Unit u in [0,2048): lane=u&63, tc=u>>6 (t=tc>>2, c=tc&3). Wp[u*8+j] holds
// the j-th bf16 of fragment bf[t][c] for that lane -> GEMM stages W with
// 32 coalesced 16B loads/lane instead of 256 scalar loads + cvts.
__global__ __launch_bounds__(256) void k_pack_w(
    const float* __restrict__ W1, u16* __restrict__ Wp1,
    const float* __restrict__ W2, u16* __restrict__ Wp2)
{
  const float* W  = blockIdx.x ? W2 : W1;
  u16*         Wp = blockIdx.x ? Wp2 : Wp1;
  for (int u = threadIdx.x; u < 2048; u += 256){
    int lane = u & 63, tc = u >> 6;
    int t = tc >> 2, c = tc & 3;
    int n = lane & 15, quad = lane >> 4;
    #pragma unroll
    for (int j=0;j<8;j++)
      Wp[(size_t)u*8 + j] = f2bf(W[(c*32 + quad*8 + j)*HD + t*16 + n]);
  }
}

// ---- init: block 0 = zero+detect dtype flags; blocks >=1 zero cnt & pooled -
// flags[0]=edge int32?, flags[1]=batch int32?, flags[2]=batch unsorted?
__global__ __launch_bounds__(256) void k_init(
    const u32* __restrict__ ei, const u32* __restrict__ bw,
    int* __restrict__ flags, int* __restrict__ cnt, float* __restrict__ pooled,
    int npairs_e, int npairs_b, int N, int npool)
{
  int t = threadIdx.x;
  if (blockIdx.x == 0){
    if (t < 16) flags[t] = 0;
    __syncthreads();
    for (int i=t; i<npairs_e; i+=256) if (ei[2*i+1] != 0) atomicOr(&flags[0], 1);
    for (int i=t; i<npairs_b; i+=256) if (bw[2*i+1] != 0) atomicOr(&flags[1], 1);
  } else {
    int i = (blockIdx.x-1)*256 + t;
    if (i < N)     cnt[i] = 0;
    if (i < npool) pooled[i] = 0.f;
  }
}

// ---- fused: blocks [0,NBc) sortedness check; blocks [NBc,..) degree count --
__global__ __launch_bounds__(256) void k_sorted_count(
    const void* __restrict__ batch, const void* __restrict__ ei,
    int* __restrict__ flags, int* __restrict__ cnt, int n, int E, int NBc)
{
  if (blockIdx.x < NBc){
    int i = blockIdx.x*256 + threadIdx.x;
    if (i < n-1){
      int is32 = flags[1];
      if (idx_at(batch, i, is32) > idx_at(batch, i+1, is32)) atomicOr(&flags[2], 1);
    }
  } else {
    int e = (blockIdx.x - NBc)*256 + threadIdx.x;
    if (e < E){
      int d = idx_at(ei, E + e, flags[0]);   // dst = row 1
      atomicAdd(&cnt[d], 1);
    }
  }
}

__global__ void k_chunk_sums(const int* __restrict__ cnt, int* __restrict__ csum, int n){
  __shared__ int sd[256];
  int c=blockIdx.x, t=threadIdx.x;
  int base=c*1024+t*4, s=0;
  #pragma unroll
  for (int k=0;k<4;k++){ int i=base+k; if(i<n) s+=cnt[i]; }
  sd[t]=s; __syncthreads();
  for (int o=128;o>0;o>>=1){ if(t<o) sd[t]+=sd[t+o]; __syncthreads(); }
  if (t==0) csum[c]=sd[0];
}

// scan chunks -> row_ptr, dinv, padded bucket cursors (gcur). The chunk-total
// scan is done inline per block (csum holds RAW sums; nch <= 1024).
__global__ void k_scan_chunks(const int* __restrict__ cnt, const int* __restrict__ csum,
                              int* __restrict__ row_ptr, int* __restrict__ gcur,
                              float* __restrict__ dinv, int n, int total, int nch){
  __shared__ int st[256];
  __shared__ int sd[256];
  int c=blockIdx.x, t=threadIdx.x;

  int s4=0;
  #pragma unroll
  for (int k=0;k<4;k++){ int i=t*4+k; if(i<nch) s4+=csum[i]; }
  st[t]=s4; __syncthreads();
  for (int o=1;o<256;o<<=1){ int x=(t>=o)?st[t-o]:0; __syncthreads(); st[t]+=x; __syncthreads(); }
  int cq=c>>2, cr=c&3;
  int cbase=(cq>0)?st[cq-1]:0;
  for (int k=0;k<cr;k++) cbase += csum[cq*4+k];

  int base=c*1024+t*4;
  int v[4], s=0;
  #pragma unroll
  for (int k=0;k<4;k++){ int i=base+k; v[k]=(i<n)?cnt[i]:0; s+=v[k]; }
  sd[t]=s; __syncthreads();
  for (int o=1;o<256;o<<=1){ int x=(t>=o)?sd[t-o]:0; __syncthreads(); sd[t]+=x; __syncthreads(); }
  int pre = cbase + ((t>0)?sd[t-1]:0);
  #pragma unroll
  for (int k=0;k<4;k++){
    int i=base+k;
    if (i<n){
      row_ptr[i]=pre;
      if ((i & ((1<<BSH)-1)) == 0) gcur[(i>>BSH)*GCUR_STRIDE] = pre;
      dinv[i]=rsqrtf((float)(v[k]+1));   // +1 self-loop; always >0
      pre+=v[k];
    }
  }
  if (c==0 && t==0) row_ptr[n]=total;
}

// ---- phase 1: LDS-staged partition of edges into dst-buckets --------------
// STANDALONE kernel (low VGPR): r3's fat-fuse with the GEMM forced 144 VGPRs
// on these blocks and cut occupancy 8->3 blocks/CU (91 us, all pipes idle).
// pairs entry: src in bits [0,24), dst_local (d & 255) in bits [24,32).
__global__ __launch_bounds__(256) void k_part1(
    const void* __restrict__ ei, const int* __restrict__ flags,
    int* __restrict__ gcur, u32* __restrict__ pairs, int E)
{
  __shared__ int hist[NBKT_MAX];
  __shared__ int soff[NBKT_MAX];
  __shared__ int gb[NBKT_MAX];
  __shared__ int scant[256];
  __shared__ u32 stage[PCHUNK];
  __shared__ u16 sbkt[PCHUNK];

  int tid = threadIdx.x;
  hist[tid]=0; hist[tid+256]=0;
  __syncthreads();

  int base = blockIdx.x*PCHUNK;
  int is32 = flags[0];
  int d[PCHUNK/256], s[PCHUNK/256];
  #pragma unroll
  for (int k=0;k<PCHUNK/256;k++){
    int e = base + k*256 + tid;
    if (e < E){
      d[k]=idx_at(ei,E+e,is32); s[k]=idx_at(ei,e,is32);
      atomicAdd(&hist[d[k]>>BSH],1);
    } else d[k]=-1;
  }
  __syncthreads();

  // scan 512 buckets with 256 threads (2 each)
  int a0=hist[2*tid], a1=hist[2*tid+1];
  scant[tid]=a0+a1; __syncthreads();
  for (int o=1;o<256;o<<=1){ int x2=(tid>=o)?scant[tid-o]:0; __syncthreads(); scant[tid]+=x2; __syncthreads(); }
  int pre = (tid>0)?scant[tid-1]:0;
  soff[2*tid]=pre; soff[2*tid+1]=pre+a0;
  if (a0) gb[2*tid]   = atomicAdd(&gcur[(2*tid)*GCUR_STRIDE],   a0); else gb[2*tid]=0;
  if (a1) gb[2*tid+1] = atomicAdd(&gcur[(2*tid+1)*GCUR_STRIDE], a1); else gb[2*tid+1]=0;
  hist[2*tid]=0; hist[2*tid+1]=0;
  __syncthreads();

  // scatter into LDS stage ordered by bucket
  #pragma unroll
  for (int k=0;k<PCHUNK/256;k++){
    if (d[k]>=0){
      int b = d[k]>>BSH;
      int loc = soff[b] + atomicAdd(&hist[b],1);
      stage[loc] = (u32)s[k] | ((u32)(d[k] & ((1<<BSH)-1)) << 24);
      sbkt[loc] = (u16)b;
    }
  }
  __syncthreads();

  // coalesced flush: consecutive slots of a bucket -> consecutive global pairs
  int cnt_edges = E - base; if (cnt_edges > PCHUNK) cnt_edges = PCHUNK;
  for (int i=tid; i<cnt_edges; i+=256){
    int b = sbkt[i];
    pairs[(size_t)gb[b] + (i - soff[b])] = stage[i];
  }
}

// ---- MFMA GEMM: G = dinv ⊙ (X @ W), bf16 out. 512-block grid (proven r2). -
// W comes PRE-PACKED (k_pack_w): staging = 32 coalesced 16B loads/lane
// (was 256 scalar f32 loads + 256 cvts -> ~half the kernel's instructions).
template <typename TIN>
__global__ __launch_bounds__(256) void k_gemm_scale(
    const TIN* __restrict__ X, const u16* __restrict__ Wp,
    const float* __restrict__ dinv, u16* __restrict__ Gout, int nrows)
{
  int lane = threadIdx.x & 63;
  int wv   = threadIdx.x >> 6;
  int n    = lane & 15, quad = lane >> 4;

  const short8* wp = reinterpret_cast<const short8*>(Wp);
  short8 bf[8][4];
  #pragma unroll
  for (int t=0;t<8;t++)
    #pragma unroll
    for (int c=0;c<4;c++)
      bf[t][c] = wp[(t*4+c)*64 + lane];

  int ntiles = (nrows+15)>>4;
  int stride = gridDim.x*4;
  for (int tile = blockIdx.x*4 + wv; tile < ntiles; tile += stride){
    int ra = tile*16 + n;                 // lane's A row (m = lane&15)
    if (ra >= nrows) ra = nrows-1;
    const TIN* xp = X + (size_t)ra*HD + quad*8;
    short8 a[4];
    #pragma unroll
    for (int c=0;c<4;c++) a[c] = load8(xp + c*32);

    f32x4 acc[8];
    #pragma unroll
    for (int t=0;t<8;t++) acc[t] = (f32x4){0.f,0.f,0.f,0.f};
    #pragma unroll
    for (int c=0;c<4;c++)
      #pragma unroll
      for (int t=0;t<8;t++)
        acc[t] = __builtin_amdgcn_mfma_f32_16x16x32_bf16(a[c], bf[t][c], acc[t], 0,0,0);

    float dv[4]; int rw[4];
    #pragma unroll
    for (int r=0;r<4;r++){
      int row = tile*16 + quad*4 + r;
      rw[r]=row; dv[r]=(row<nrows)?dinv[row]:0.f;
    }
    #pragma unroll
    for (int t=0;t<8;t++)
      #pragma unroll
      for (int r=0;r<4;r++){
        int row = rw[r];
        if (row < nrows)
          Gout[(size_t)row*HD + t*16 + n] = f2bf(dv[r]*acc[t][r]);
      }
  }
}

// ---- phase 2: per-bucket exact scatter, LDS cursors -----------------------
__global__ __launch_bounds__(256) void k_part2(
    const u32* __restrict__ pairs, const int* __restrict__ row_ptr,
    int* __restrict__ colv, int N)
{
  __shared__ int lcur[1<<BSH];
  int b = blockIdx.x;
  int n0 = b<<BSH;
  int n1 = (b+1)<<BSH; if (n1 > N) n1 = N;
  int nn = n1 - n0;
  for (int i=threadIdx.x; i<nn; i+=256) lcur[i] = row_ptr[n0+i];
  __syncthreads();
  int lo = row_ptr[n0], hi = row_ptr[n1];
  for (int i = lo + threadIdx.x; i < hi; i += 256){
    u32 p = pairs[i];
    int s = (int)(p & 0xFFFFFFu), dl = (int)(p >> 24);
    int pos = atomicAdd(&lcur[dl], 1);
    colv[pos] = s;
  }
}

// ---- aggregation v3: h[i]=relu(dinv[i]*(g[i]+sum g[src])+b) ---------------
// One wave/node, u32 row loads (instruction-count frozen per edge: r1's +45%
// instr variant regressed 25%). v3 deepens the batch ladder 16->8->4->scalar:
// 2x MLP on deg>=16 nodes and a halved serial tail, at IDENTICAL per-edge
// instruction cost. If this is neutral, the gather is service-rate-bound.
__global__ __launch_bounds__(256) void k_aggregate(
    const u16* __restrict__ g, const int* __restrict__ row_ptr,
    const int* __restrict__ colv, const float* __restrict__ dinv,
    const float* __restrict__ bias, u16* __restrict__ h, int n)
{
  int node = blockIdx.x*4 + (threadIdx.x>>6);
  if (node >= n) return;
  int lane = threadIdx.x & 63;
  int off = lane*2;

  u32 u = *reinterpret_cast<const u32*>(g + (size_t)node*HD + off);   // self-loop term
  float ax = blo(u), ay = bhi(u);

  int s = row_ptr[node], e = row_ptr[node+1];
  int i = s;
  for (; i+16<=e; i+=16){
    u32 v[16];
    #pragma unroll
    for (int j=0;j<16;j++)
      v[j] = *reinterpret_cast<const u32*>(g+(size_t)colv[i+j]*HD+off);
    #pragma unroll
    for (int j=0;j<16;j++){ ax += blo(v[j]); ay += bhi(v[j]); }
  }
  if (i+8<=e){
    u32 v[8];
    #pragma unroll
    for (int j=0;j<8;j++)
      v[j] = *reinterpret_cast<const u32*>(g+(size_t)colv[i+j]*HD+off);
    #pragma unroll
    for (int j=0;j<8;j++){ ax += blo(v[j]); ay += bhi(v[j]); }
    i += 8;
  }
  if (i+4<=e){
    u32 v[4];
    #pragma unroll
    for (int j=0;j<4;j++)
      v[j] = *reinterpret_cast<const u32*>(g+(size_t)colv[i+j]*HD+off);
    #pragma unroll
    for (int j=0;j<4;j++){ ax += blo(v[j]); ay += bhi(v[j]); }
    i += 4;
  }
  for (; i<e; i++){
    u32 v=*reinterpret_cast<const u32*>(g+(size_t)colv[i]*HD+off);
    ax += blo(v); ay += bhi(v);
  }

  float dv = dinv[node];
  float rx = fmaxf(fmaf(dv, ax, bias[off]),   0.f);
  float ry = fmaxf(fmaf(dv, ay, bias[off+1]), 0.f);
  *reinterpret_cast<u32*>(h + (size_t)node*HD + off) = (u32)f2bf(rx) | ((u32)f2bf(ry)<<16);
}

// ---- global_add_pool + final linear, sorted path (fused) ------------------
__device__ __forceinline__ int lowerb(const void* a, int is32, int n, int key){
  int lo=0, hi=n;
  while (lo<hi){
    int mid=(lo+hi)>>1;
    if (idx_at(a, mid, is32) < key) lo=mid+1; else hi=mid;
  }
  return lo;
}

__global__ __launch_bounds__(256) void k_pool_final_sorted(
    const u16* __restrict__ h, const void* __restrict__ batch,
    const int* __restrict__ flags, const float* __restrict__ Wl,
    const float* __restrict__ bl, float* __restrict__ out, int n)
{
  if (flags[2]) return;                     // unsorted -> atomic path handles it
  __shared__ float sd[4][128];
  __shared__ float ps[128];
  __shared__ float racc[4][64];
  int gid = blockIdx.x, t = threadIdx.x;
  int w = t >> 6, lane = t & 63;
  int off = lane*2;
  int is32 = flags[1];
  int lo = lowerb(batch, is32, n, gid), hi = lowerb(batch, is32, n, gid+1);

  float ax = 0.f, ay = 0.f;
  int i = lo + w;                           // waves stride rows by 4
  for (; i + 12 < hi; i += 16){
    u32 v0 = *reinterpret_cast<const u32*>(h + (size_t)(i   )*HD + off);
    u32 v1 = *reinterpret_cast<const u32*>(h + (size_t)(i+ 4)*HD + off);
    u32 v2 = *reinterpret_cast<const u32*>(h + (size_t)(i+ 8)*HD + off);
    u32 v3 = *reinterpret_cast<const u32*>(h + (size_t)(i+12)*HD + off);
    ax += blo(v0)+blo(v1)+blo(v2)+blo(v3);
    ay += bhi(v0)+bhi(v1)+bhi(v2)+bhi(v3);
  }
  for (; i < hi; i += 4){
    u32 v = *reinterpret_cast<const u32*>(h + (size_t)i*HD + off);
    ax += blo(v); ay += bhi(v);
  }
  sd[w][off] = ax; sd[w][off+1] = ay;
  __syncthreads();
  if (t < 128) ps[t] = sd[0][t] + sd[1][t] + sd[2][t] + sd[3][t];
  __syncthreads();

  // out[gid] = ps @ Wl + bl : 4 k-segments of 32, 64 outputs each
  int o = t & 63, seg = t >> 6;
  float acc = 0.f;
  #pragma unroll
  for (int kk=0; kk<32; kk++){
    int k = seg*32 + kk;
    acc = fmaf(ps[k], Wl[k*OUTD + o], acc);
  }
  racc[seg][o] = acc;
  __syncthreads();
  if (t < 64)
    out[(size_t)gid*OUTD + t] = bl[t] + racc[0][t] + racc[1][t] + racc[2][t] + racc[3][t];
}

// ---- global_add_pool, fallback: atomicAdd per node (any ordering) ---------
// Grid-stride at 1024 blocks: the sorted path previously paid 25k
// empty-block dispatches here.
__global__ __launch_bounds__(256) void k_pool_atomic(
    const u16* __restrict__ h, const void* __restrict__ batch,
    const int* __restrict__ flags, float* __restrict__ pooled, int n)
{
  if (!flags[2]) return;                    // sorted path already did it
  int lane = threadIdx.x & 63;
  int off = lane*2;
  int is32 = flags[1];
  for (int node = blockIdx.x*4 + (threadIdx.x>>6); node < n; node += gridDim.x*4){
    int g = idx_at(batch, node, is32);
    u32 v = *reinterpret_cast<const u32*>(h + (size_t)node*HD + off);
    atomicAdd(&pooled[(size_t)g*HD + off],     blo(v));
    atomicAdd(&pooled[(size_t)g*HD + off + 1], bhi(v));
  }
}

// ---- final linear, unsorted path only: out = pooled @ Wl + bl -------------
__global__ void k_final(const float* __restrict__ pooled, const float* __restrict__ Wl,
                        const float* __restrict__ bl, const int* __restrict__ flags,
                        float* __restrict__ out){
  if (!flags[2]) return;                    // sorted path wrote out already
  int gid = blockIdx.x, t = threadIdx.x;   // 64 threads
  float acc = bl[t];
  const float* p = pooled + gid*HD;
  #pragma unroll 8
  for (int k=0;k<HD;k++) acc = fmaf(p[k], Wl[k*OUTD + t], acc);
  out[gid*OUTD + t] = acc;
}

extern "C" void kernel_launch(void* const* d_in, const int* in_sizes, int n_in,
                              void* d_out, int out_size, void* d_ws, size_t ws_size,
                              hipStream_t stream)
{
  const float* x   = (const float*)d_in[0];
  const void*  ei  = d_in[1];
  const void*  bat = d_in[2];
  const float* W1  = (const float*)d_in[3];
  const float* b1  = (const float*)d_in[4];
  const float* W2  = (const float*)d_in[5];
  const float* b2  = (const float*)d_in[6];
  const float* Wl  = (const float*)d_in[7];
  const float* bl  = (const float*)d_in[8];
  float* out = (float*)d_out;

  int N = in_sizes[0] / HD;
  int E = in_sizes[1] / 2;
  int G = out_size / OUTD;
  int NCH = (N + 1023) / 1024;
  int nbins = (N + (1<<BSH) - 1) >> BSH;   // 256 nodes per bin

  char* w = (char*)d_ws;
  size_t o = 0;
  auto alloc = [&](size_t b){ void* p = w + o; o += (b + 255) & ~(size_t)255; return p; };
  int*   cnt     = (int*)  alloc((size_t)N*4);
  int*   row_ptr = (int*)  alloc((size_t)(N+1)*4);
  int*   csum    = (int*)  alloc((size_t)NCH*4);
  int*   colv    = (int*)  alloc((size_t)E*4);
  u32*   pairs   = (u32*)  alloc((size_t)E*4);
  int*   gcur    = (int*)  alloc((size_t)NBKT_MAX*GCUR_STRIDE*4);
  float* dinv    = (float*)alloc((size_t)N*4);
  u16*   gbuf    = (u16*)  alloc((size_t)N*HD*2);
  u16*   hbuf    = (u16*)  alloc((size_t)N*HD*2);
  float* pooled  = (float*)alloc((size_t)G*HD*4);
  u16*   wp1     = (u16*)  alloc((size_t)HD*HD*2);
  u16*   wp2     = (u16*)  alloc((size_t)HD*HD*2);
  int*   flags   = (int*)  alloc(256);
  (void)n_in;

  if (o > ws_size || nbins > NBKT_MAX){
    k_zero_out<<<(out_size+255)/256, 256, 0, stream>>>(out, out_size);
    return;
  }

  int npairs_e = 4096; if (npairs_e > E) npairs_e = E;
  int npairs_b = 4096; if (npairs_b > N/2) npairs_b = N/2;
  int npool = G*HD;
  int nzb = (N+255)/256; { int pz = (npool+255)/256; if (pz > nzb) nzb = pz; }

  // 0: pre-pack W1/W2 into MFMA fragment layout (independent of everything)
  k_pack_w<<<2, 256, 0, stream>>>(W1, wp1, W2, wp2);
  // 1: zero flags/cnt/pooled + dtype detection
  k_init<<<1+nzb, 256, 0, stream>>>((const u32*)ei, (const u32*)bat, flags, cnt, pooled,
                                    npairs_e, npairs_b, N, npool);
  // 2: sortedness check (blocks [0,NBc)) + degree count (rest)
  int NBc = (N+255)/256, NBe = (E+255)/256;
  k_sorted_count<<<NBc+NBe, 256, 0, stream>>>(bat, ei, flags, cnt, N, E, NBc);
  // 3-4: scan (chunk-total scan folded into k_scan_chunks)
  k_chunk_sums <<<NCH, 256, 0, stream>>>(cnt, csum, N);
  k_scan_chunks<<<NCH, 256, 0, stream>>>(cnt, csum, row_ptr, gcur, dinv, N, E, NCH);
  // 5-6: partition (separate dispatches; see k_part1 comment re r3 fusion)
  int npart = (E + PCHUNK - 1) / PCHUNK;
  k_part1<<<npart, 256, 0, stream>>>(ei, flags, gcur, pairs, E);
  k_gemm_scale<float><<<512, 256, 0, stream>>>(x, wp1, dinv, gbuf, N);
  k_part2<<<nbins, 256, 0, stream>>>(pairs, row_ptr, colv, N);
  // 7-9: aggregate L1, GEMM L2, aggregate L2
  k_aggregate <<<(N+3)/4, 256, 0, stream>>>(gbuf, row_ptr, colv, dinv, b1, hbuf, N);
  k_gemm_scale<u16><<<512, 256, 0, stream>>>(hbuf, wp2, dinv, gbuf, N);
  k_aggregate <<<(N+3)/4, 256, 0, stream>>>(gbuf, row_ptr, colv, dinv, b2, hbuf, N);
  // 10-12: pool+final (sorted fused path; atomic fallback early-returns)
  k_pool_final_sorted<<<G, 256, 0, stream>>>(hbuf, bat, flags, Wl, bl, out, N);
  k_pool_atomic<<<1024, 256, 0, stream>>>(hbuf, bat, flags, pooled, N);
  k_final      <<<G, OUTD, 0, stream>>>(pooled, Wl, bl, flags, out);
}

// Round 7
// 369.626 us; speedup vs baseline: 1.3293x; 1.1439x over previous
//
#include <hip/hip_runtime.h>
#include <hip/hip_bf16.h>

typedef unsigned short u16;
typedef unsigned int   u32;
typedef unsigned long long u64;
typedef long long      i64;
typedef __attribute__((ext_vector_type(8))) short short8;  // 8 bf16 raw
typedef __attribute__((ext_vector_type(4))) float f32x4;

#define HD 128   // hidden / input feature dim
#define OUTD 64  // final output dim
#define BSH 8            // bucket shift: 256 nodes per bucket (power of 2, <=8 for u32 pack!)
#define NBKT_MAX 512     // max buckets (N <= 128K; also keeps src in 24 bits)
#define PCHUNK 2048      // edges per block in partition phase 1
#define EPB 4096         // edges per block in bucket histogram
#define GCUR_STRIDE 16   // ints; 64 B padding to avoid atomic line contention

__device__ __forceinline__ float bf2f(u16 u){ union{u32 i; float f;} x; x.i=((u32)u)<<16; return x.f; }
__device__ __forceinline__ u16 f2bf(float f){ __hip_bfloat16 h=__float2bfloat16(f); return *reinterpret_cast<u16*>(&h); }
__device__ __forceinline__ float blo(u32 v){ union{u32 i; float f;} x; x.i=v<<16; return x.f; }
__device__ __forceinline__ float bhi(u32 v){ union{u32 i; float f;} x; x.i=v&0xffff0000u; return x.f; }

__device__ __forceinline__ short8 load8(const float* p){
  f32x4 lo = *reinterpret_cast<const f32x4*>(p);
  f32x4 hi = *reinterpret_cast<const f32x4*>(p + 4);
  short8 r;
  #pragma unroll
  for (int j=0;j<4;j++){ r[j]=(short)f2bf(lo[j]); r[4+j]=(short)f2bf(hi[j]); }
  return r;
}
__device__ __forceinline__ short8 load8(const u16* p){
  return *reinterpret_cast<const short8*>(p);
}

// index fetch that handles int32-vs-int64 delivery (flag: 1 = int32, 0 = int64)
__device__ __forceinline__ int idx_at(const void* p, int i, int is32){
  return is32 ? ((const int*)p)[i] : (int)((const i64*)p)[i];
}

// ---- zero-fill output (ws-too-small fallback signal) ----------------------
__global__ void k_zero_out(float* __restrict__ out, int n){
  int i = blockIdx.x*256 + threadIdx.x;
  if (i < n) out[i] = 0.f;
}

// ---- weight pre-pack: W (f32 row-major) -> bf16 fragment-major ------------
__global__ __launch_bounds__(256) void k_pack_w(
    const float* __restrict__ W1, u16* __restrict__ Wp1,
    const float* __restrict__ W2, u16* __restrict__ Wp2)
{
  const float* W  = blockIdx.x ? W2 : W1;
  u16*         Wp = blockIdx.x ? Wp2 : Wp1;
  for (int u = threadIdx.x; u < 2048; u += 256){
    int lane = u & 63, tc = u >> 6;
    int t = tc >> 2, c = tc & 3;
    int n = lane & 15, quad = lane >> 4;
    #pragma unroll
    for (int j=0;j<8;j++)
      Wp[(size_t)u*8 + j] = f2bf(W[(c*32 + quad*8 + j)*HD + t*16 + n]);
  }
}

// ---- init: block 0 = zero+detect dtype flags; blocks >=1 zero bcntp/pooled -
// flags[0]=edge int32?, flags[1]=batch int32?, flags[2]=batch unsorted?
__global__ __launch_bounds__(256) void k_init(
    const u32* __restrict__ ei, const u32* __restrict__ bw,
    int* __restrict__ flags, int* __restrict__ bcntp, float* __restrict__ pooled,
    int npairs_e, int npairs_b, int nbc, int npool)
{
  int t = threadIdx.x;
  if (blockIdx.x == 0){
    if (t < 16) flags[t] = 0;
    __syncthreads();
    for (int i=t; i<npairs_e; i+=256) if (ei[2*i+1] != 0) atomicOr(&flags[0], 1);
    for (int i=t; i<npairs_b; i+=256) if (bw[2*i+1] != 0) atomicOr(&flags[1], 1);
  } else {
    int i = (blockIdx.x-1)*256 + t;
    if (i < nbc)   bcntp[i] = 0;
    if (i < npool) pooled[i] = 0.f;
  }
}

// ---- bucket histogram + sortedness check ----------------------------------
// Replaces the 1.6M-random-global-atomic degree count (65.8us, WRITE=1.6M*32B
// atomic storm ping-ponging across 8 XCD L2s). LDS 512-bin histogram/block,
// then 2 padded-line global atomics per thread. Per-NODE degrees are derived
// later, bucket-locally, in k_part2ex.
__global__ __launch_bounds__(256) void k_bucket_sorted(
    const void* __restrict__ batch, const void* __restrict__ ei,
    int* __restrict__ flags, int* __restrict__ bcntp, int n, int E, int NBc)
{
  __shared__ int hist[NBKT_MAX];
  int tid = threadIdx.x;
  if (blockIdx.x < NBc){
    int i = blockIdx.x*256 + tid;
    if (i < n-1){
      int is32 = flags[1];
      if (idx_at(batch, i, is32) > idx_at(batch, i+1, is32)) atomicOr(&flags[2], 1);
    }
    return;
  }
  hist[tid]=0; hist[tid+256]=0;
  __syncthreads();
  int base = (blockIdx.x - NBc)*EPB;
  int is32 = flags[0];
  #pragma unroll
  for (int k=0;k<EPB/256;k++){
    int e = base + k*256 + tid;
    if (e < E){
      int d = idx_at(ei, E + e, is32);   // dst = row 1
      atomicAdd(&hist[d>>BSH], 1);
    }
  }
  __syncthreads();
  int a0=hist[2*tid], a1=hist[2*tid+1];
  if (a0) atomicAdd(&bcntp[(2*tid)*GCUR_STRIDE],   a0);
  if (a1) atomicAdd(&bcntp[(2*tid+1)*GCUR_STRIDE], a1);
}

// ---- 512-bucket exclusive scan -> bucket bases (gcur for part1, bbase) ----
__global__ __launch_bounds__(256) void k_bucket_scan(
    const int* __restrict__ bcntp, int* __restrict__ gcur, int* __restrict__ bbase,
    int* __restrict__ row_ptr, int N, int E)
{
  __shared__ int scant[256];
  int t = threadIdx.x;
  int a0 = bcntp[(2*t)*GCUR_STRIDE], a1 = bcntp[(2*t+1)*GCUR_STRIDE];
  scant[t] = a0 + a1; __syncthreads();
  for (int o=1;o<256;o<<=1){ int x=(t>=o)?scant[t-o]:0; __syncthreads(); scant[t]+=x; __syncthreads(); }
  int pre = (t>0)?scant[t-1]:0;
  gcur[(2*t)*GCUR_STRIDE]   = pre;      bbase[2*t]   = pre;
  gcur[(2*t+1)*GCUR_STRIDE] = pre + a0; bbase[2*t+1] = pre + a0;
  if (t == 255){ bbase[512] = pre + a0 + a1; row_ptr[N] = E; }
}

// ---- phase 1: LDS-staged partition of edges into dst-buckets --------------
// STANDALONE kernel (low VGPR): r3's fat-fuse with the GEMM forced 144 VGPRs
// on these blocks and cut occupancy 8->3 blocks/CU (91 us, all pipes idle).
// pairs entry: src in bits [0,24), dst_local (d & 255) in bits [24,32).
__global__ __launch_bounds__(256) void k_part1(
    const void* __restrict__ ei, const int* __restrict__ flags,
    int* __restrict__ gcur, u32* __restrict__ pairs, int E)
{
  __shared__ int hist[NBKT_MAX];
  __shared__ int soff[NBKT_MAX];
  __shared__ int gb[NBKT_MAX];
  __shared__ int scant[256];
  __shared__ u32 stage[PCHUNK];
  __shared__ u16 sbkt[PCHUNK];

  int tid = threadIdx.x;
  hist[tid]=0; hist[tid+256]=0;
  __syncthreads();

  int base = blockIdx.x*PCHUNK;
  int is32 = flags[0];
  int d[PCHUNK/256], s[PCHUNK/256];
  #pragma unroll
  for (int k=0;k<PCHUNK/256;k++){
    int e = base + k*256 + tid;
    if (e < E){
      d[k]=idx_at(ei,E+e,is32); s[k]=idx_at(ei,e,is32);
      atomicAdd(&hist[d[k]>>BSH],1);
    } else d[k]=-1;
  }
  __syncthreads();

  // scan 512 buckets with 256 threads (2 each)
  int a0=hist[2*tid], a1=hist[2*tid+1];
  scant[tid]=a0+a1; __syncthreads();
  for (int o=1;o<256;o<<=1){ int x2=(tid>=o)?scant[tid-o]:0; __syncthreads(); scant[tid]+=x2; __syncthreads(); }
  int pre = (tid>0)?scant[tid-1]:0;
  soff[2*tid]=pre; soff[2*tid+1]=pre+a0;
  if (a0) gb[2*tid]   = atomicAdd(&gcur[(2*tid)*GCUR_STRIDE],   a0); else gb[2*tid]=0;
  if (a1) gb[2*tid+1] = atomicAdd(&gcur[(2*tid+1)*GCUR_STRIDE], a1); else gb[2*tid+1]=0;
  hist[2*tid]=0; hist[2*tid+1]=0;
  __syncthreads();

  // scatter into LDS stage ordered by bucket
  #pragma unroll
  for (int k=0;k<PCHUNK/256;k++){
    if (d[k]>=0){
      int b = d[k]>>BSH;
      int loc = soff[b] + atomicAdd(&hist[b],1);
      stage[loc] = (u32)s[k] | ((u32)(d[k] & ((1<<BSH)-1)) << 24);
      sbkt[loc] = (u16)b;
    }
  }
  __syncthreads();

  // coalesced flush: consecutive slots of a bucket -> consecutive global pairs
  int cnt_edges = E - base; if (cnt_edges > PCHUNK) cnt_edges = PCHUNK;
  for (int i=tid; i<cnt_edges; i+=256){
    int b = sbkt[i];
    pairs[(size_t)gb[b] + (i - soff[b])] = stage[i];
  }
}

// ---- phase 2ex: bucket-local count + scan -> row_ptr, dinv, exact scatter -
// Per-node degree is derived HERE (LDS count of the bucket's pairs window),
// eliminating the global per-node atomic count and the N-wide scan kernels.
// Defensive: lcur fully initialized + scatter pos clamped to bucket window
// (uninitialized-LDS -> wild global store was the one fault candidate found
// in the r6 audit after the container double-failure).
__global__ __launch_bounds__(256) void k_part2ex(
    const u32* __restrict__ pairs, const int* __restrict__ bbase,
    int* __restrict__ row_ptr, float* __restrict__ dinv,
    int* __restrict__ colv, int N)
{
  __shared__ int lcnt[1<<BSH];
  __shared__ int sscan[256];
  __shared__ int lcur[1<<BSH];
  int b = blockIdx.x, t = threadIdx.x;
  int n0 = b<<BSH;
  int nn = N - n0; if (nn > 256) nn = 256;
  int lo = bbase[b], hi = bbase[b+1];
  lcnt[t] = 0; lcur[t] = lo;
  __syncthreads();
  for (int i = lo + t; i < hi; i += 256)
    atomicAdd(&lcnt[pairs[i] >> 24], 1);
  __syncthreads();
  int c = lcnt[t];
  sscan[t] = c; __syncthreads();
  for (int o=1;o<256;o<<=1){ int x=(t>=o)?sscan[t-o]:0; __syncthreads(); sscan[t]+=x; __syncthreads(); }
  int pre = (t>0)?sscan[t-1]:0;
  if (t < nn){
    row_ptr[n0+t] = lo + pre;
    dinv[n0+t]    = rsqrtf((float)(c+1));   // +1 self-loop; always >0
    lcur[t]       = lo + pre;
  }
  __syncthreads();
  for (int i = lo + t; i < hi; i += 256){
    u32 p = pairs[i];
    int pos = atomicAdd(&lcur[p>>24], 1);
    if (pos >= lo && pos < hi) colv[pos] = (int)(p & 0xFFFFFFu);
  }
}

// ---- MFMA GEMM: G = dinv ⊙ (X @ W), bf16 out. 512-block grid (proven r2). -
// W comes PRE-PACKED (k_pack_w): staging = 32 coalesced 16B loads/lane.
template <typename TIN>
__global__ __launch_bounds__(256) void k_gemm_scale(
    const TIN* __restrict__ X, const u16* __restrict__ Wp,
    const float* __restrict__ dinv, u16* __restrict__ Gout, int nrows)
{
  int lane = threadIdx.x & 63;
  int wv   = threadIdx.x >> 6;
  int n    = lane & 15, quad = lane >> 4;

  const short8* wp = reinterpret_cast<const short8*>(Wp);
  short8 bf[8][4];
  #pragma unroll
  for (int t=0;t<8;t++)
    #pragma unroll
    for (int c=0;c<4;c++)
      bf[t][c] = wp[(t*4+c)*64 + lane];

  int ntiles = (nrows+15)>>4;
  int stride = gridDim.x*4;
  for (int tile = blockIdx.x*4 + wv; tile < ntiles; tile += stride){
    int ra = tile*16 + n;                 // lane's A row (m = lane&15)
    if (ra >= nrows) ra = nrows-1;
    const TIN* xp = X + (size_t)ra*HD + quad*8;
    short8 a[4];
    #pragma unroll
    for (int c=0;c<4;c++) a[c] = load8(xp + c*32);

    f32x4 acc[8];
    #pragma unroll
    for (int t=0;t<8;t++) acc[t] = (f32x4){0.f,0.f,0.f,0.f};
    #pragma unroll
    for (int c=0;c<4;c++)
      #pragma unroll
      for (int t=0;t<8;t++)
        acc[t] = __builtin_amdgcn_mfma_f32_16x16x32_bf16(a[c], bf[t][c], acc[t], 0,0,0);

    float dv[4]; int rw[4];
    #pragma unroll
    for (int r=0;r<4;r++){
      int row = tile*16 + quad*4 + r;
      rw[r]=row; dv[r]=(row<nrows)?dinv[row]:0.f;
    }
    #pragma unroll
    for (int t=0;t<8;t++)
      #pragma unroll
      for (int r=0;r<4;r++){
        int row = rw[r];
        if (row < nrows)
          Gout[(size_t)row*HD + t*16 + n] = f2bf(dv[r]*acc[t][r]);
      }
  }
}

// ---- aggregation v3 (FROZEN): h[i]=relu(dinv[i]*(g[i]+sum g[src])+b) ------
// One wave/node, u32 row loads, 16->8->4->scalar ladder. Service-rate-bound
// (FETCH ~190MB = XCD-compulsory floor). Do NOT add per-edge instructions.
__global__ __launch_bounds__(256) void k_aggregate(
    const u16* __restrict__ g, const int* __restrict__ row_ptr,
    const int* __restrict__ colv, const float* __restrict__ dinv,
    const float* __restrict__ bias, u16* __restrict__ h, int n)
{
  int node = blockIdx.x*4 + (threadIdx.x>>6);
  if (node >= n) return;
  int lane = threadIdx.x & 63;
  int off = lane*2;

  u32 u = *reinterpret_cast<const u32*>(g + (size_t)node*HD + off);   // self-loop term
  float ax = blo(u), ay = bhi(u);

  int s = row_ptr[node], e = row_ptr[node+1];
  int i = s;
  for (; i+16<=e; i+=16){
    u32 v[16];
    #pragma unroll
    for (int j=0;j<16;j++)
      v[j] = *reinterpret_cast<const u32*>(g+(size_t)colv[i+j]*HD+off);
    #pragma unroll
    for (int j=0;j<16;j++){ ax += blo(v[j]); ay += bhi(v[j]); }
  }
  if (i+8<=e){
    u32 v[8];
    #pragma unroll
    for (int j=0;j<8;j++)
      v[j] = *reinterpret_cast<const u32*>(g+(size_t)colv[i+j]*HD+off);
    #pragma unroll
    for (int j=0;j<8;j++){ ax += blo(v[j]); ay += bhi(v[j]); }
    i += 8;
  }
  if (i+4<=e){
    u32 v[4];
    #pragma unroll
    for (int j=0;j<4;j++)
      v[j] = *reinterpret_cast<const u32*>(g+(size_t)colv[i+j]*HD+off);
    #pragma unroll
    for (int j=0;j<4;j++){ ax += blo(v[j]); ay += bhi(v[j]); }
    i += 4;
  }
  for (; i<e; i++){
    u32 v=*reinterpret_cast<const u32*>(g+(size_t)colv[i]*HD+off);
    ax += blo(v); ay += bhi(v);
  }

  float dv = dinv[node];
  float rx = fmaxf(fmaf(dv, ax, bias[off]),   0.f);
  float ry = fmaxf(fmaf(dv, ay, bias[off+1]), 0.f);
  *reinterpret_cast<u32*>(h + (size_t)node*HD + off) = (u32)f2bf(rx) | ((u32)f2bf(ry)<<16);
}

// ---- global_add_pool + final linear, sorted path (fused) ------------------
__device__ __forceinline__ int lowerb(const void* a, int is32, int n, int key){
  int lo=0, hi=n;
  while (lo<hi){
    int mid=(lo+hi)>>1;
    if (idx_at(a, mid, is32) < key) lo=mid+1; else hi=mid;
  }
  return lo;
}

__global__ __launch_bounds__(256) void k_pool_final_sorted(
    const u16* __restrict__ h, const void* __restrict__ batch,
    const int* __restrict__ flags, const float* __restrict__ Wl,
    const float* __restrict__ bl, float* __restrict__ out, int n)
{
  if (flags[2]) return;                     // unsorted -> atomic path handles it
  __shared__ float sd[4][128];
  __shared__ float ps[128];
  __shared__ float racc[4][64];
  int gid = blockIdx.x, t = threadIdx.x;
  int w = t >> 6, lane = t & 63;
  int off = lane*2;
  int is32 = flags[1];
  int lo = lowerb(batch, is32, n, gid), hi = lowerb(batch, is32, n, gid+1);

  float ax = 0.f, ay = 0.f;
  int i = lo + w;                           // waves stride rows by 4
  for (; i + 12 < hi; i += 16){
    u32 v0 = *reinterpret_cast<const u32*>(h + (size_t)(i   )*HD + off);
    u32 v1 = *reinterpret_cast<const u32*>(h + (size_t)(i+ 4)*HD + off);
    u32 v2 = *reinterpret_cast<const u32*>(h + (size_t)(i+ 8)*HD + off);
    u32 v3 = *reinterpret_cast<const u32*>(h + (size_t)(i+12)*HD + off);
    ax += blo(v0)+blo(v1)+blo(v2)+blo(v3);
    ay += bhi(v0)+bhi(v1)+bhi(v2)+bhi(v3);
  }
  for (; i < hi; i += 4){
    u32 v = *reinterpret_cast<const u32*>(h + (size_t)i*HD + off);
    ax += blo(v); ay += bhi(v);
  }
  sd[w][off] = ax; sd[w][off+1] = ay;
  __syncthreads();
  if (t < 128) ps[t] = sd[0][t] + sd[1][t] + sd[2][t] + sd[3][t];
  __syncthreads();

  // out[gid] = ps @ Wl + bl : 4 k-segments of 32, 64 outputs each
  int o = t & 63, seg = t >> 6;
  float acc = 0.f;
  #pragma unroll
  for (int kk=0; kk<32; kk++){
    int k = seg*32 + kk;
    acc = fmaf(ps[k], Wl[k*OUTD + o], acc);
  }
  racc[seg][o] = acc;
  __syncthreads();
  if (t < 64)
    out[(size_t)gid*OUTD + t] = bl[t] + racc[0][t] + racc[1][t] + racc[2][t] + racc[3][t];
}

// ---- global_add_pool, fallback: atomicAdd per node (any ordering) ---------
__global__ __launch_bounds__(256) void k_pool_atomic(
    const u16* __restrict__ h, const void* __restrict__ batch,
    const int* __restrict__ flags, float* __restrict__ pooled, int n)
{
  if (!flags[2]) return;                    // sorted path already did it
  int lane = threadIdx.x & 63;
  int off = lane*2;
  int is32 = flags[1];
  for (int node = blockIdx.x*4 + (threadIdx.x>>6); node < n; node += gridDim.x*4){
    int g = idx_at(batch, node, is32);
    u32 v = *reinterpret_cast<const u32*>(h + (size_t)node*HD + off);
    atomicAdd(&pooled[(size_t)g*HD + off],     blo(v));
    atomicAdd(&pooled[(size_t)g*HD + off + 1], bhi(v));
  }
}

// ---- final linear, unsorted path only: out = pooled @ Wl + bl -------------
__global__ void k_final(const float* __restrict__ pooled, const float* __restrict__ Wl,
                        const float* __restrict__ bl, const int* __restrict__ flags,
                        float* __restrict__ out){
  if (!flags[2]) return;                    // sorted path wrote out already
  int gid = blockIdx.x, t = threadIdx.x;   // 64 threads
  float acc = bl[t];
  const float* p = pooled + gid*HD;
  #pragma unroll 8
  for (int k=0;k<HD;k++) acc = fmaf(p[k], Wl[k*OUTD + t], acc);
  out[gid*OUTD + t] = acc;
}

extern "C" void kernel_launch(void* const* d_in, const int* in_sizes, int n_in,
                              void* d_out, int out_size, void* d_ws, size_t ws_size,
                              hipStream_t stream)
{
  const float* x   = (const float*)d_in[0];
  const void*  ei  = d_in[1];
  const void*  bat = d_in[2];
  const float* W1  = (const float*)d_in[3];
  const float* b1  = (const float*)d_in[4];
  const float* W2  = (const float*)d_in[5];
  const float* b2  = (const float*)d_in[6];
  const float* Wl  = (const float*)d_in[7];
  const float* bl  = (const float*)d_in[8];
  float* out = (float*)d_out;

  int N = in_sizes[0] / HD;
  int E = in_sizes[1] / 2;
  int G = out_size / OUTD;
  int nbins = (N + (1<<BSH) - 1) >> BSH;   // 256 nodes per bin

  char* w = (char*)d_ws;
  size_t o = 0;
  auto alloc = [&](size_t b){ void* p = w + o; o += (b + 255) & ~(size_t)255; return p; };
  int*   row_ptr = (int*)  alloc((size_t)(N+1)*4);
  int*   colv    = (int*)  alloc((size_t)E*4);
  u32*   pairs   = (u32*)  alloc((size_t)E*4);
  int*   gcur    = (int*)  alloc((size_t)NBKT_MAX*GCUR_STRIDE*4);
  int*   bcntp   = (int*)  alloc((size_t)NBKT_MAX*GCUR_STRIDE*4);
  int*   bbase   = (int*)  alloc((size_t)(NBKT_MAX+1)*4);
  float* dinv    = (float*)alloc((size_t)N*4);
  u16*   gbuf    = (u16*)  alloc((size_t)N*HD*2);
  u16*   hbuf    = (u16*)  alloc((size_t)N*HD*2);
  float* pooled  = (float*)alloc((size_t)G*HD*4);
  u16*   wp1     = (u16*)  alloc((size_t)HD*HD*2);
  u16*   wp2     = (u16*)  alloc((size_t)HD*HD*2);
  int*   flags   = (int*)  alloc(256);
  (void)n_in;

  if (o > ws_size || nbins > NBKT_MAX){
    k_zero_out<<<(out_size+255)/256, 256, 0, stream>>>(out, out_size);
    return;
  }

  int npairs_e = 4096; if (npairs_e > E) npairs_e = E;
  int npairs_b = 4096; if (npairs_b > N/2) npairs_b = N/2;
  int npool = G*HD;
  int nbc = NBKT_MAX*GCUR_STRIDE;
  int nzb = (npool+255)/256; { int bz = (nbc+255)/256; if (bz > nzb) nzb = bz; }

  // 0: pre-pack W1/W2 into MFMA fragment layout
  k_pack_w<<<2, 256, 0, stream>>>(W1, wp1, W2, wp2);
  // 1: zero flags/bcntp/pooled + dtype detection
  k_init<<<1+nzb, 256, 0, stream>>>((const u32*)ei, (const u32*)bat, flags, bcntp, pooled,
                                    npairs_e, npairs_b, nbc, npool);
  // 2: sortedness check + LDS-staged bucket histogram (replaces atomic storm)
  int NBc = (N+255)/256, NPB = (E+EPB-1)/EPB;
  k_bucket_sorted<<<NBc+NPB, 256, 0, stream>>>(bat, ei, flags, bcntp, N, E, NBc);
  // 3: 512-bucket scan -> gcur + bbase
  k_bucket_scan<<<1, 256, 0, stream>>>(bcntp, gcur, bbase, row_ptr, N, E);
  // 4: partition phase 1 (bucket-region-ordered pairs)
  int npart = (E + PCHUNK - 1) / PCHUNK;
  k_part1<<<npart, 256, 0, stream>>>(ei, flags, gcur, pairs, E);
  // 5: bucket-local count/scan -> row_ptr + dinv + exact colv scatter
  k_part2ex<<<nbins, 256, 0, stream>>>(pairs, bbase, row_ptr, dinv, colv, N);
  // 6-9: GEMM L1, aggregate L1, GEMM L2, aggregate L2
  k_gemm_scale<float><<<512, 256, 0, stream>>>(x, wp1, dinv, gbuf, N);
  k_aggregate <<<(N+3)/4, 256, 0, stream>>>(gbuf, row_ptr, colv, dinv, b1, hbuf, N);
  k_gemm_scale<u16><<<512, 256, 0, stream>>>(hbuf, wp2, dinv, gbuf, N);
  k_aggregate <<<(N+3)/4, 256, 0, stream>>>(gbuf, row_ptr, colv, dinv, b2, hbuf, N);
  // 10-12: pool+final (sorted fused path; atomic fallback early-returns)
  k_pool_final_sorted<<<G, 256, 0, stream>>>(hbuf, bat, flags, Wl, bl, out, N);
  k_pool_atomic<<<1024, 256, 0, stream>>>(hbuf, bat, flags, pooled, N);
  k_final      <<<G, OUTD, 0, stream>>>(pooled, Wl, bl, flags, out);
}